// Round 1
// baseline (176.532 us; speedup 1.0000x reference)
//
#include <hip/hip_runtime.h>
#include <math.h>

// Model_78271484002488: B=8, L=512, D=32, N_PATCHES=16, N_REF=32, LAT=128, HM=4,
// FH=8, NL=3, FF=128, PRED=96.  All f32.

#define ISQ32 0.17677669529663687f   // 1/sqrt(32)
#define C128  (-0.07195578415606394f)  // -ln(1e4)/128
#define C32   (-0.28782313662425575f)  // -ln(1e4)/32

// ---------------------------------------------------------------------------
// K0: rows 0..4095 -> Kmat[row][128] = time_embed(x_mark[row],128) @ Wk
//     rows 4096..4607 -> Qall[qr][128] = time_embed(qr*512/511,128) @ Wq
// one wave per row, 4 rows/block
__global__ void k_embed_mm(const float* __restrict__ x_mark,
                           const float* __restrict__ Wk,
                           const float* __restrict__ Wq,
                           float* __restrict__ Kmat,
                           float* __restrict__ Qall) {
    __shared__ float sTe[4][128];
    const int wave = threadIdx.x >> 6;
    const int lane = threadIdx.x & 63;
    const int row = blockIdx.x * 4 + wave;
    float t;
    const float* W;
    float* outp;
    if (row < 4096) {
        t = x_mark[row];
        W = Wk;
        outp = Kmat + row * 128;
    } else {
        const int qr = row - 4096;
        t = (float)qr * (512.0f / 511.0f);
        W = Wq;
        outp = Qall + qr * 128;
    }
    const float dv = expf((float)(2 * lane) * C128);
    const float ang = t * dv;
    sTe[wave][2 * lane]     = sinf(ang);
    sTe[wave][2 * lane + 1] = cosf(ang);
    __syncthreads();
    float a0 = 0.f, a1 = 0.f;
    #pragma unroll 8
    for (int k = 0; k < 128; ++k) {
        const float te = sTe[wave][k];
        a0 = fmaf(te, W[k * 128 + lane], a0);
        a1 = fmaf(te, W[k * 128 + lane + 64], a1);
    }
    outp[lane] = a0;
    outp[lane + 64] = a1;
}

// ---------------------------------------------------------------------------
// K0b: obsBits[b*512+l] = bitmask over d of (x_mask[b,l,d] > 0)
// one wave handles two (b,l) rows via ballot
__global__ void k_obsbits(const float* __restrict__ x_mask,
                          unsigned* __restrict__ obsBits) {
    const int gt = blockIdx.x * 256 + threadIdx.x;
    const int w = gt >> 6, lane = gt & 63;
    const int bl = w * 2 + (lane >> 5);
    const int d = lane & 31;
    const unsigned long long m = __ballot(x_mask[bl * 32 + d] > 0.0f);
    if (lane == 0)  obsBits[w * 2]     = (unsigned)(m & 0xffffffffull);
    if (lane == 32) obsBits[w * 2 + 1] = (unsigned)(m >> 32);
}

// ---------------------------------------------------------------------------
// K1: fused patch attention.  block = (i,b,h); 256 threads.
// attn[i][b][r][h*32+d] = sum_l e[r,l]*cN(l,d)*x[b,l,d] / sum_l e[r,l]*cD(l,d)
__launch_bounds__(256)
__global__ void k_patch_attn(const float* __restrict__ x,
                             const float* __restrict__ x_mark,
                             const unsigned* __restrict__ obsBits,
                             const float* __restrict__ Kmat,
                             const float* __restrict__ Qall,
                             float* __restrict__ attn) {
    __shared__ float sS[16][516];     // scores/e, half of r at a time
    __shared__ float sQ[32][32];
    __shared__ unsigned sEffN[512];   // holds obs bits, then effN (numerator mask)
    __shared__ unsigned sEffD[512];   // holds inp flag, then effD (denominator mask)
    __shared__ unsigned sAV;
    const int tid = threadIdx.x;
    const int h = blockIdx.x & 3;
    const int b = (blockIdx.x >> 2) & 7;
    const int i = blockIdx.x >> 5;
    const float e0 = 32.0f * (float)i, e1 = 32.0f * (float)(i + 1);
    if (tid == 0) sAV = 0u;
    __syncthreads();
    unsigned avp = 0u;
    #pragma unroll
    for (int k = 0; k < 2; ++k) {
        const int l = tid + 256 * k;
        const float t = x_mark[b * 512 + l];
        const unsigned bits = obsBits[b * 512 + l];
        const unsigned inp = (t >= e0 && t <= e1 && bits != 0u) ? 1u : 0u;
        sEffN[l] = bits;
        sEffD[l] = inp;
        if (inp) avp |= bits;
    }
    #pragma unroll
    for (int off = 32; off > 0; off >>= 1) avp |= __shfl_xor(avp, off);
    if ((tid & 63) == 0) atomicOr(&sAV, avp);
    #pragma unroll
    for (int k = 0; k < 4; ++k) {
        const int idx = tid + 256 * k;
        const int r = idx >> 5, e = idx & 31;
        sQ[r][e] = Qall[(i * 32 + r) * 128 + h * 32 + e];
    }
    __syncthreads();
    const unsigned av = sAV;
    // rewrite own entries into effective masks (each thread touches only its l's)
    #pragma unroll
    for (int k = 0; k < 2; ++k) {
        const int l = tid + 256 * k;
        const unsigned bits = sEffN[l];
        const unsigned effD = (sEffD[l] ? bits : 0u) | ~av;
        sEffD[l] = effD;
        sEffN[l] = effD & bits;
    }

    for (int rh = 0; rh < 2; ++rh) {
        if (rh) __syncthreads();   // sS reuse: phase D of previous half must be done
        // ---- Phase B: scores for r in [rh*16, rh*16+16), all l ----
        #pragma unroll
        for (int hl = 0; hl < 2; ++hl) {
            const int l = tid + 256 * hl;
            if (sEffD[l] != 0u) {
                const float* Kp = Kmat + (b * 512 + l) * 128 + h * 32;
                float kr[32];
                #pragma unroll
                for (int e = 0; e < 32; ++e) kr[e] = Kp[e];
                #pragma unroll
                for (int rl = 0; rl < 16; ++rl) {
                    const int r = rh * 16 + rl;
                    float p0 = 0.f, p1 = 0.f, p2 = 0.f, p3 = 0.f;
                    #pragma unroll
                    for (int e = 0; e < 32; e += 4) {
                        p0 = fmaf(sQ[r][e],     kr[e],     p0);
                        p1 = fmaf(sQ[r][e + 1], kr[e + 1], p1);
                        p2 = fmaf(sQ[r][e + 2], kr[e + 2], p2);
                        p3 = fmaf(sQ[r][e + 3], kr[e + 3], p3);
                    }
                    sS[rl][l] = (p0 + p1 + p2 + p3) * ISQ32;
                }
            } else {
                #pragma unroll
                for (int rl = 0; rl < 16; ++rl) sS[rl][l] = 0.0f;
            }
        }
        __syncthreads();
        // ---- Phase C: e = exp(s - rowmax); rowmax shift is softmax-invariant ----
        {
            const int wv = tid >> 6, lane = tid & 63;
            #pragma unroll
            for (int rr = 0; rr < 4; ++rr) {
                const int rl = wv * 4 + rr;
                float vals[8];
                float m = -1e30f;
                #pragma unroll
                for (int k = 0; k < 8; ++k) {
                    vals[k] = sS[rl][lane + 64 * k];
                    m = fmaxf(m, vals[k]);
                }
                #pragma unroll
                for (int off = 32; off > 0; off >>= 1) m = fmaxf(m, __shfl_xor(m, off));
                #pragma unroll
                for (int k = 0; k < 8; ++k) sS[rl][lane + 64 * k] = __expf(vals[k] - m);
            }
        }
        __syncthreads();
        // ---- Phase D: masked weighted sums; skip l with no contribution ----
        {
            const int rl = tid >> 4, dg = tid & 15;
            float num0 = 0.f, den0 = 0.f, num1 = 0.f, den1 = 0.f;
            for (int l = 0; l < 512; ++l) {
                const unsigned effD = sEffD[l];
                if (effD == 0u) continue;           // wave-uniform skip
                const unsigned effN = sEffN[l];
                const float el = sS[rl][l];
                const float* xp = x + (b * 512 + l) * 32;
                const float x0 = xp[dg], x1 = xp[dg + 16];
                if ((effD >> dg) & 1u)        den0 += el;
                if ((effN >> dg) & 1u)        num0 = fmaf(el, x0, num0);
                if ((effD >> (dg + 16)) & 1u) den1 += el;
                if ((effN >> (dg + 16)) & 1u) num1 = fmaf(el, x1, num1);
            }
            const int r = rh * 16 + rl;
            float* ap = attn + (((i * 8 + b) * 32 + r) * 128) + h * 32;
            ap[dg]      = num0 / den0;
            ap[dg + 16] = num1 / den1;
        }
    }
}

// ---------------------------------------------------------------------------
// K2: reprs = attn(B,32,128) @ W_out + b_out;  z[(b*32+d)][i][r] = reprs + te16(i,r)
__global__ void k_reprs(const float* __restrict__ attn,
                        const float* __restrict__ W_out,
                        const float* __restrict__ b_out,
                        float* __restrict__ z) {
    __shared__ float sA[32][129];
    const int tid = threadIdx.x;
    const int b = blockIdx.x & 7;
    const int i = blockIdx.x >> 3;
    #pragma unroll
    for (int k = 0; k < 16; ++k) {
        const int idx = tid + 256 * k;
        sA[idx >> 7][idx & 127] = attn[(i * 8 + b) * 4096 + idx];
    }
    __syncthreads();
    const int r = tid & 31, dgrp = tid >> 5;
    float acc0 = 0.f, acc1 = 0.f, acc2 = 0.f, acc3 = 0.f;
    for (int k = 0; k < 128; ++k) {
        const float a = sA[r][k];
        acc0 = fmaf(a, W_out[k * 32 + dgrp],      acc0);
        acc1 = fmaf(a, W_out[k * 32 + dgrp + 8],  acc1);
        acc2 = fmaf(a, W_out[k * 32 + dgrp + 16], acc2);
        acc3 = fmaf(a, W_out[k * 32 + dgrp + 24], acc3);
    }
    const float dv = expf((float)(2 * (r >> 1)) * C32);
    const float ang = (float)i * dv;
    const float pe = (r & 1) ? cosf(ang) : sinf(ang);
    const int base = i * 32 + r;
    z[(b * 32 + dgrp)      * 512 + base] = acc0 + b_out[dgrp]      + pe;
    z[(b * 32 + dgrp + 8)  * 512 + base] = acc1 + b_out[dgrp + 8]  + pe;
    z[(b * 32 + dgrp + 16) * 512 + base] = acc2 + b_out[dgrp + 16] + pe;
    z[(b * 32 + dgrp + 24) * 512 + base] = acc3 + b_out[dgrp + 24] + pe;
}

// ---------------------------------------------------------------------------
// K3: 3-layer transformer (S=16, dm=32, 8 heads of 4) + final LN + head.
// one block per sequence n (256 blocks)
__launch_bounds__(256)
__global__ void k_former(const float* __restrict__ z,
                         const float* __restrict__ f_Wq, const float* __restrict__ f_Wk,
                         const float* __restrict__ f_Wv, const float* __restrict__ f_Wo,
                         const float* __restrict__ f_bq, const float* __restrict__ f_bk,
                         const float* __restrict__ f_bv, const float* __restrict__ f_bo,
                         const float* __restrict__ f_ln1_g, const float* __restrict__ f_ln1_b,
                         const float* __restrict__ f_W1, const float* __restrict__ f_b1,
                         const float* __restrict__ f_W2, const float* __restrict__ f_b2,
                         const float* __restrict__ f_ln2_g, const float* __restrict__ f_ln2_b,
                         const float* __restrict__ ln_f_g, const float* __restrict__ ln_f_b,
                         const float* __restrict__ W_lin, const float* __restrict__ b_lin,
                         float* __restrict__ out) {
    __shared__ float sZ[16][33], sQ[16][33], sK[16][33], sV[16][33], sO[16][33], sT[16][33];
    __shared__ float sH[16][129];
    __shared__ float sMu[16], sRs[16];
    const int tid = threadIdx.x;
    const int n = blockIdx.x;
    #pragma unroll
    for (int k = 0; k < 2; ++k) {
        const int idx = tid + 256 * k;
        sZ[idx >> 5][idx & 31] = z[n * 512 + idx];
    }
    __syncthreads();
    for (int layer = 0; layer < 3; ++layer) {
        const float* Wq = f_Wq + layer * 1024; const float* bq = f_bq + layer * 32;
        const float* Wk = f_Wk + layer * 1024; const float* bk = f_bk + layer * 32;
        const float* Wv = f_Wv + layer * 1024; const float* bv = f_bv + layer * 32;
        const float* Wo = f_Wo + layer * 1024; const float* bo = f_bo + layer * 32;
        const float* W1 = f_W1 + layer * 4096; const float* b1 = f_b1 + layer * 128;
        const float* W2 = f_W2 + layer * 4096; const float* b2 = f_b2 + layer * 32;
        // QKV projections
        #pragma unroll
        for (int it = 0; it < 6; ++it) {
            const int idx = tid + 256 * it;
            const int which = idx >> 9, rem = idx & 511, s = rem >> 5, j = rem & 31;
            const float* W = (which == 0) ? Wq : ((which == 1) ? Wk : Wv);
            const float* bb = (which == 0) ? bq : ((which == 1) ? bk : bv);
            float acc = bb[j];
            #pragma unroll
            for (int k = 0; k < 32; ++k) acc = fmaf(sZ[s][k], W[k * 32 + j], acc);
            if (which == 0) sQ[s][j] = acc;
            else if (which == 1) sK[s][j] = acc;
            else sV[s][j] = acc;
        }
        __syncthreads();
        // attention per (head, q-token)
        if (tid < 128) {
            const int hh = tid >> 4, q = tid & 15;
            float sc[16];
            float mx = -1e30f;
            #pragma unroll
            for (int k = 0; k < 16; ++k) {
                float a = 0.f;
                #pragma unroll
                for (int e = 0; e < 4; ++e) a = fmaf(sQ[q][hh * 4 + e], sK[k][hh * 4 + e], a);
                sc[k] = a * 0.5f;
                mx = fmaxf(mx, sc[k]);
            }
            float sum = 0.f;
            #pragma unroll
            for (int k = 0; k < 16; ++k) { sc[k] = __expf(sc[k] - mx); sum += sc[k]; }
            const float inv = 1.0f / sum;
            #pragma unroll
            for (int e = 0; e < 4; ++e) {
                float a = 0.f;
                #pragma unroll
                for (int k = 0; k < 16; ++k) a = fmaf(sc[k], sV[k][hh * 4 + e], a);
                sO[q][hh * 4 + e] = a * inv;
            }
        }
        __syncthreads();
        // O projection + residual
        #pragma unroll
        for (int it = 0; it < 2; ++it) {
            const int idx = tid + 256 * it, s = idx >> 5, j = idx & 31;
            float acc = bo[j];
            #pragma unroll
            for (int k = 0; k < 32; ++k) acc = fmaf(sO[s][k], Wo[k * 32 + j], acc);
            sT[s][j] = sZ[s][j] + acc;
        }
        __syncthreads();
        if (tid < 16) {
            float mu = 0.f, m2 = 0.f;
            #pragma unroll
            for (int j = 0; j < 32; ++j) { const float v = sT[tid][j]; mu += v; m2 += v * v; }
            mu *= (1.0f / 32.0f); m2 *= (1.0f / 32.0f);
            sMu[tid] = mu;
            sRs[tid] = rsqrtf(m2 - mu * mu + 1e-5f);
        }
        __syncthreads();
        {
            const float* g = f_ln1_g + layer * 32; const float* be = f_ln1_b + layer * 32;
            #pragma unroll
            for (int it = 0; it < 2; ++it) {
                const int idx = tid + 256 * it, s = idx >> 5, j = idx & 31;
                sZ[s][j] = (sT[s][j] - sMu[s]) * sRs[s] * g[j] + be[j];
            }
        }
        __syncthreads();
        // FFN1 + gelu(tanh approx, jax default)
        #pragma unroll
        for (int it = 0; it < 8; ++it) {
            const int idx = tid + 256 * it, s = idx >> 7, f = idx & 127;
            float acc = b1[f];
            #pragma unroll
            for (int k = 0; k < 32; ++k) acc = fmaf(sZ[s][k], W1[k * 128 + f], acc);
            const float c = acc;
            const float t3 = 0.7978845608028654f * (c + 0.044715f * c * c * c);
            sH[s][f] = 0.5f * c * (1.0f + tanhf(t3));
        }
        __syncthreads();
        // FFN2 + residual
        #pragma unroll
        for (int it = 0; it < 2; ++it) {
            const int idx = tid + 256 * it, s = idx >> 5, j = idx & 31;
            float acc = b2[j];
            for (int k = 0; k < 128; ++k) acc = fmaf(sH[s][k], W2[k * 32 + j], acc);
            sT[s][j] = sZ[s][j] + acc;
        }
        __syncthreads();
        if (tid < 16) {
            float mu = 0.f, m2 = 0.f;
            #pragma unroll
            for (int j = 0; j < 32; ++j) { const float v = sT[tid][j]; mu += v; m2 += v * v; }
            mu *= (1.0f / 32.0f); m2 *= (1.0f / 32.0f);
            sMu[tid] = mu;
            sRs[tid] = rsqrtf(m2 - mu * mu + 1e-5f);
        }
        __syncthreads();
        {
            const float* g = f_ln2_g + layer * 32; const float* be = f_ln2_b + layer * 32;
            #pragma unroll
            for (int it = 0; it < 2; ++it) {
                const int idx = tid + 256 * it, s = idx >> 5, j = idx & 31;
                sZ[s][j] = (sT[s][j] - sMu[s]) * sRs[s] * g[j] + be[j];
            }
        }
        __syncthreads();
    }
    // final LN (in place: each element read/written by exactly one thread)
    if (tid < 16) {
        float mu = 0.f, m2 = 0.f;
        #pragma unroll
        for (int j = 0; j < 32; ++j) { const float v = sZ[tid][j]; mu += v; m2 += v * v; }
        mu *= (1.0f / 32.0f); m2 *= (1.0f / 32.0f);
        sMu[tid] = mu;
        sRs[tid] = rsqrtf(m2 - mu * mu + 1e-5f);
    }
    __syncthreads();
    #pragma unroll
    for (int it = 0; it < 2; ++it) {
        const int idx = tid + 256 * it, s = idx >> 5, j = idx & 31;
        sZ[s][j] = (sZ[s][j] - sMu[s]) * sRs[s] * ln_f_g[j] + ln_f_b[j];
    }
    __syncthreads();
    // head: out[b, o, d] = sum_{j=r*16+p} sZ[p][r] * W_lin[j][o] + b_lin[o]
    if (tid < 96) {
        float acc = b_lin[tid];
        for (int j = 0; j < 512; ++j)
            acc = fmaf(sZ[j & 15][j >> 4], W_lin[j * 96 + tid], acc);
        out[((n >> 5) * 96 + tid) * 32 + (n & 31)] = acc;
    }
}

// ---------------------------------------------------------------------------
extern "C" void kernel_launch(void* const* d_in, const int* in_sizes, int n_in,
                              void* d_out, int out_size, void* d_ws, size_t ws_size,
                              hipStream_t stream) {
    const float* x       = (const float*)d_in[0];
    const float* x_mark  = (const float*)d_in[1];
    const float* x_mask  = (const float*)d_in[2];
    const float* Wq      = (const float*)d_in[3];
    const float* Wk      = (const float*)d_in[4];
    const float* W_out   = (const float*)d_in[5];
    const float* b_out   = (const float*)d_in[6];
    const float* f_Wq    = (const float*)d_in[7];
    const float* f_Wk    = (const float*)d_in[8];
    const float* f_Wv    = (const float*)d_in[9];
    const float* f_Wo    = (const float*)d_in[10];
    const float* f_bq    = (const float*)d_in[11];
    const float* f_bk    = (const float*)d_in[12];
    const float* f_bv    = (const float*)d_in[13];
    const float* f_bo    = (const float*)d_in[14];
    const float* f_ln1_g = (const float*)d_in[15];
    const float* f_ln1_b = (const float*)d_in[16];
    const float* f_W1    = (const float*)d_in[17];
    const float* f_b1    = (const float*)d_in[18];
    const float* f_W2    = (const float*)d_in[19];
    const float* f_b2    = (const float*)d_in[20];
    const float* f_ln2_g = (const float*)d_in[21];
    const float* f_ln2_b = (const float*)d_in[22];
    const float* ln_f_g  = (const float*)d_in[23];
    const float* ln_f_b  = (const float*)d_in[24];
    const float* W_lin   = (const float*)d_in[25];
    const float* b_lin   = (const float*)d_in[26];

    float* ws = (float*)d_ws;
    float* Kmat      = ws;                      // 4096*128 = 524288
    float* Qall      = ws + 524288;             // 512*128  = 65536
    unsigned* obsB   = (unsigned*)(ws + 589824);// 4096 words
    float* attn      = ws + 593920;             // 16*8*32*128 = 524288
    float* zbuf      = ws + 1118208;            // 256*16*32 = 131072   (total ~5.0 MB)

    k_embed_mm<<<1152, 256, 0, stream>>>(x_mark, Wk, Wq, Kmat, Qall);
    k_obsbits<<<512, 256, 0, stream>>>(x_mask, obsB);
    k_patch_attn<<<512, 256, 0, stream>>>(x, x_mark, obsB, Kmat, Qall, attn);
    k_reprs<<<128, 256, 0, stream>>>(attn, W_out, b_out, zbuf);
    k_former<<<256, 256, 0, stream>>>(zbuf,
        f_Wq, f_Wk, f_Wv, f_Wo, f_bq, f_bk, f_bv, f_bo,
        f_ln1_g, f_ln1_b, f_W1, f_b1, f_W2, f_b2, f_ln2_g, f_ln2_b,
        ln_f_g, ln_f_b, W_lin, b_lin, (float*)d_out);
}

// Round 2
// 130.811 us; speedup vs baseline: 1.3495x; 1.3495x over previous
//
#include <hip/hip_runtime.h>
#include <math.h>

// Model_78271484002488: B=8, L=512, D=32, N_PATCHES=16, N_REF=32, LAT=128, HM=4,
// FH=8, NL=3, FF=128, PRED=96.  All f32.

#define ISQ32 0.17677669529663687f   // 1/sqrt(32)
#define C128  (-0.07195578415606394f)  // -ln(1e4)/128
#define C32   (-0.28782313662425575f)  // -ln(1e4)/32

// ---------------------------------------------------------------------------
// K0: rows 0..4095 -> Kmat[row][128] = time_embed(x_mark[row],128) @ Wk
//     rows 4096..4607 -> Qall[qr][128] = time_embed(qr*512/511,128) @ Wq
__global__ void k_embed_mm(const float* __restrict__ x_mark,
                           const float* __restrict__ Wk,
                           const float* __restrict__ Wq,
                           float* __restrict__ Kmat,
                           float* __restrict__ Qall) {
    __shared__ float sTe[4][128];
    const int wave = threadIdx.x >> 6;
    const int lane = threadIdx.x & 63;
    const int row = blockIdx.x * 4 + wave;
    float t;
    const float* W;
    float* outp;
    if (row < 4096) {
        t = x_mark[row];
        W = Wk;
        outp = Kmat + row * 128;
    } else {
        const int qr = row - 4096;
        t = (float)qr * (512.0f / 511.0f);
        W = Wq;
        outp = Qall + qr * 128;
    }
    const float dv = expf((float)(2 * lane) * C128);
    const float ang = t * dv;
    sTe[wave][2 * lane]     = sinf(ang);
    sTe[wave][2 * lane + 1] = cosf(ang);
    __syncthreads();
    float a0 = 0.f, a1 = 0.f;
    #pragma unroll 8
    for (int k = 0; k < 128; ++k) {
        const float te = sTe[wave][k];
        a0 = fmaf(te, W[k * 128 + lane], a0);
        a1 = fmaf(te, W[k * 128 + lane + 64], a1);
    }
    outp[lane] = a0;
    outp[lane + 64] = a1;
}

// ---------------------------------------------------------------------------
// K0b: obsBits[b*512+l] = bitmask over d of (x_mask[b,l,d] > 0)
__global__ void k_obsbits(const float* __restrict__ x_mask,
                          unsigned* __restrict__ obsBits) {
    const int gt = blockIdx.x * 256 + threadIdx.x;
    const int w = gt >> 6, lane = gt & 63;
    const int bl = w * 2 + (lane >> 5);
    const int d = lane & 31;
    const unsigned long long m = __ballot(x_mask[bl * 32 + d] > 0.0f);
    if (lane == 0)  obsBits[w * 2]     = (unsigned)(m & 0xffffffffull);
    if (lane == 32) obsBits[w * 2 + 1] = (unsigned)(m >> 32);
}

// ---------------------------------------------------------------------------
// K1: fused patch attention.  block = (i,b,h); 256 threads.
__launch_bounds__(256)
__global__ void k_patch_attn(const float* __restrict__ x,
                             const float* __restrict__ x_mark,
                             const unsigned* __restrict__ obsBits,
                             const float* __restrict__ Kmat,
                             const float* __restrict__ Qall,
                             float* __restrict__ attn) {
    __shared__ float sS[16][516];
    __shared__ float sQ[32][32];
    __shared__ unsigned sEffN[512];
    __shared__ unsigned sEffD[512];
    __shared__ unsigned sAV;
    const int tid = threadIdx.x;
    const int h = blockIdx.x & 3;
    const int b = (blockIdx.x >> 2) & 7;
    const int i = blockIdx.x >> 5;
    const float e0 = 32.0f * (float)i, e1 = 32.0f * (float)(i + 1);
    if (tid == 0) sAV = 0u;
    __syncthreads();
    unsigned avp = 0u;
    #pragma unroll
    for (int k = 0; k < 2; ++k) {
        const int l = tid + 256 * k;
        const float t = x_mark[b * 512 + l];
        const unsigned bits = obsBits[b * 512 + l];
        const unsigned inp = (t >= e0 && t <= e1 && bits != 0u) ? 1u : 0u;
        sEffN[l] = bits;
        sEffD[l] = inp;
        if (inp) avp |= bits;
    }
    #pragma unroll
    for (int off = 32; off > 0; off >>= 1) avp |= __shfl_xor(avp, off);
    if ((tid & 63) == 0) atomicOr(&sAV, avp);
    #pragma unroll
    for (int k = 0; k < 4; ++k) {
        const int idx = tid + 256 * k;
        const int r = idx >> 5, e = idx & 31;
        sQ[r][e] = Qall[(i * 32 + r) * 128 + h * 32 + e];
    }
    __syncthreads();
    const unsigned av = sAV;
    #pragma unroll
    for (int k = 0; k < 2; ++k) {
        const int l = tid + 256 * k;
        const unsigned bits = sEffN[l];
        const unsigned effD = (sEffD[l] ? bits : 0u) | ~av;
        sEffD[l] = effD;
        sEffN[l] = effD & bits;
    }

    for (int rh = 0; rh < 2; ++rh) {
        if (rh) __syncthreads();
        #pragma unroll
        for (int hl = 0; hl < 2; ++hl) {
            const int l = tid + 256 * hl;
            if (sEffD[l] != 0u) {
                const float* Kp = Kmat + (b * 512 + l) * 128 + h * 32;
                float kr[32];
                #pragma unroll
                for (int e = 0; e < 32; ++e) kr[e] = Kp[e];
                #pragma unroll
                for (int rl = 0; rl < 16; ++rl) {
                    const int r = rh * 16 + rl;
                    float p0 = 0.f, p1 = 0.f, p2 = 0.f, p3 = 0.f;
                    #pragma unroll
                    for (int e = 0; e < 32; e += 4) {
                        p0 = fmaf(sQ[r][e],     kr[e],     p0);
                        p1 = fmaf(sQ[r][e + 1], kr[e + 1], p1);
                        p2 = fmaf(sQ[r][e + 2], kr[e + 2], p2);
                        p3 = fmaf(sQ[r][e + 3], kr[e + 3], p3);
                    }
                    sS[rl][l] = (p0 + p1 + p2 + p3) * ISQ32;
                }
            } else {
                #pragma unroll
                for (int rl = 0; rl < 16; ++rl) sS[rl][l] = 0.0f;
            }
        }
        __syncthreads();
        {
            const int wv = tid >> 6, lane = tid & 63;
            #pragma unroll
            for (int rr = 0; rr < 4; ++rr) {
                const int rl = wv * 4 + rr;
                float vals[8];
                float m = -1e30f;
                #pragma unroll
                for (int k = 0; k < 8; ++k) {
                    vals[k] = sS[rl][lane + 64 * k];
                    m = fmaxf(m, vals[k]);
                }
                #pragma unroll
                for (int off = 32; off > 0; off >>= 1) m = fmaxf(m, __shfl_xor(m, off));
                #pragma unroll
                for (int k = 0; k < 8; ++k) sS[rl][lane + 64 * k] = __expf(vals[k] - m);
            }
        }
        __syncthreads();
        {
            const int rl = tid >> 4, dg = tid & 15;
            float num0 = 0.f, den0 = 0.f, num1 = 0.f, den1 = 0.f;
            for (int l = 0; l < 512; ++l) {
                const unsigned effD = sEffD[l];
                if (effD == 0u) continue;
                const unsigned effN = sEffN[l];
                const float el = sS[rl][l];
                const float* xp = x + (b * 512 + l) * 32;
                const float x0 = xp[dg], x1 = xp[dg + 16];
                if ((effD >> dg) & 1u)        den0 += el;
                if ((effN >> dg) & 1u)        num0 = fmaf(el, x0, num0);
                if ((effD >> (dg + 16)) & 1u) den1 += el;
                if ((effN >> (dg + 16)) & 1u) num1 = fmaf(el, x1, num1);
            }
            const int r = rh * 16 + rl;
            float* ap = attn + (((i * 8 + b) * 32 + r) * 128) + h * 32;
            ap[dg]      = num0 / den0;
            ap[dg + 16] = num1 / den1;
        }
    }
}

// ---------------------------------------------------------------------------
// K2: reprs = attn(B,32,128) @ W_out + b_out;  z[(b*32+d)][i][r] = reprs + te16(i,r)
__global__ void k_reprs(const float* __restrict__ attn,
                        const float* __restrict__ W_out,
                        const float* __restrict__ b_out,
                        float* __restrict__ z) {
    __shared__ float sA[32][129];
    const int tid = threadIdx.x;
    const int b = blockIdx.x & 7;
    const int i = blockIdx.x >> 3;
    #pragma unroll
    for (int k = 0; k < 16; ++k) {
        const int idx = tid + 256 * k;
        sA[idx >> 7][idx & 127] = attn[(i * 8 + b) * 4096 + idx];
    }
    __syncthreads();
    const int r = tid & 31, dgrp = tid >> 5;
    float acc0 = 0.f, acc1 = 0.f, acc2 = 0.f, acc3 = 0.f;
    #pragma unroll 8
    for (int k = 0; k < 128; ++k) {
        const float a = sA[r][k];
        acc0 = fmaf(a, W_out[k * 32 + dgrp],      acc0);
        acc1 = fmaf(a, W_out[k * 32 + dgrp + 8],  acc1);
        acc2 = fmaf(a, W_out[k * 32 + dgrp + 16], acc2);
        acc3 = fmaf(a, W_out[k * 32 + dgrp + 24], acc3);
    }
    const float dv = expf((float)(2 * (r >> 1)) * C32);
    const float ang = (float)i * dv;
    const float pe = (r & 1) ? cosf(ang) : sinf(ang);
    const int base = i * 32 + r;
    z[(b * 32 + dgrp)      * 512 + base] = acc0 + b_out[dgrp]      + pe;
    z[(b * 32 + dgrp + 8)  * 512 + base] = acc1 + b_out[dgrp + 8]  + pe;
    z[(b * 32 + dgrp + 16) * 512 + base] = acc2 + b_out[dgrp + 16] + pe;
    z[(b * 32 + dgrp + 24) * 512 + base] = acc3 + b_out[dgrp + 24] + pe;
}

// ---------------------------------------------------------------------------
// K3: 3-layer transformer (S=16, dm=32, 8 heads of 4) + final LN + head.
// One block per sequence n.  All per-layer weights staged into LDS; all inner
// loops run on LDS with full unrolling.  LayerNorm via 16-lane shfl butterflies.
__launch_bounds__(256)
__global__ void k_former(const float* __restrict__ z,
                         const float* __restrict__ f_Wq, const float* __restrict__ f_Wk,
                         const float* __restrict__ f_Wv, const float* __restrict__ f_Wo,
                         const float* __restrict__ f_bq, const float* __restrict__ f_bk,
                         const float* __restrict__ f_bv, const float* __restrict__ f_bo,
                         const float* __restrict__ f_ln1_g, const float* __restrict__ f_ln1_b,
                         const float* __restrict__ f_W1, const float* __restrict__ f_b1,
                         const float* __restrict__ f_W2, const float* __restrict__ f_b2,
                         const float* __restrict__ f_ln2_g, const float* __restrict__ f_ln2_b,
                         const float* __restrict__ ln_f_g, const float* __restrict__ ln_f_b,
                         const float* __restrict__ W_lin, const float* __restrict__ b_lin,
                         float* __restrict__ out) {
    __shared__ float sZ[16][33], sQ[16][33], sK[16][33], sV[16][33], sO[16][33], sT[16][33];
    __shared__ float sH[16][129];
    __shared__ float sWq[1024], sWk[1024], sWv[1024], sWo[1024];
    __shared__ float sW1[4096], sW2[4096];
    __shared__ float sBq[32], sBk[32], sBv[32], sBo[32], sB1[128], sB2[32];
    __shared__ float sL1g[32], sL1b[32], sL2g[32], sL2b[32];
    __shared__ float sZf[512];
    __shared__ float sPart[2][96];
    const int tid = threadIdx.x;
    const int n = blockIdx.x;
    #pragma unroll
    for (int k = 0; k < 2; ++k) {
        const int idx = tid + 256 * k;
        sZ[idx >> 5][idx & 31] = z[n * 512 + idx];
    }
    for (int layer = 0; layer < 3; ++layer) {
        // ---- stage this layer's weights into LDS (coalesced float4 burst) ----
        ((float4*)sWq)[tid] = ((const float4*)(f_Wq + layer * 1024))[tid];
        ((float4*)sWk)[tid] = ((const float4*)(f_Wk + layer * 1024))[tid];
        ((float4*)sWv)[tid] = ((const float4*)(f_Wv + layer * 1024))[tid];
        ((float4*)sWo)[tid] = ((const float4*)(f_Wo + layer * 1024))[tid];
        #pragma unroll
        for (int k2 = 0; k2 < 4; ++k2) {
            ((float4*)sW1)[tid + 256 * k2] = ((const float4*)(f_W1 + layer * 4096))[tid + 256 * k2];
            ((float4*)sW2)[tid + 256 * k2] = ((const float4*)(f_W2 + layer * 4096))[tid + 256 * k2];
        }
        {
            const int j = tid & 31;
            switch (tid >> 5) {
                case 0: sBq[j]  = f_bq[layer * 32 + j];    break;
                case 1: sBk[j]  = f_bk[layer * 32 + j];    break;
                case 2: sBv[j]  = f_bv[layer * 32 + j];    break;
                case 3: sBo[j]  = f_bo[layer * 32 + j];    break;
                case 4: sB2[j]  = f_b2[layer * 32 + j];    break;
                case 5: sL1g[j] = f_ln1_g[layer * 32 + j]; break;
                case 6: sL1b[j] = f_ln1_b[layer * 32 + j]; break;
                case 7: sL2g[j] = f_ln2_g[layer * 32 + j]; break;
            }
            if (tid < 128) sB1[tid] = f_b1[layer * 128 + tid];
            else if (tid < 160) sL2b[tid - 128] = f_ln2_b[layer * 32 + (tid - 128)];
        }
        __syncthreads();   // b1: weights + sZ ready
        // ---- QKV projections (all from LDS) ----
        #pragma unroll
        for (int it = 0; it < 6; ++it) {
            const int idx = tid + 256 * it;
            const int which = idx >> 9, rem = idx & 511, s = rem >> 5, j = rem & 31;
            const float* W  = (which == 0) ? sWq : ((which == 1) ? sWk : sWv);
            const float* bb = (which == 0) ? sBq : ((which == 1) ? sBk : sBv);
            float acc = bb[j];
            #pragma unroll
            for (int k = 0; k < 32; ++k) acc = fmaf(sZ[s][k], W[k * 32 + j], acc);
            if (which == 0) sQ[s][j] = acc;
            else if (which == 1) sK[s][j] = acc;
            else sV[s][j] = acc;
        }
        __syncthreads();   // b2
        // ---- attention per (head, q-token) ----
        if (tid < 128) {
            const int hh = tid >> 4, q = tid & 15;
            float sc[16];
            float mx = -1e30f;
            #pragma unroll
            for (int k = 0; k < 16; ++k) {
                float a = 0.f;
                #pragma unroll
                for (int e = 0; e < 4; ++e) a = fmaf(sQ[q][hh * 4 + e], sK[k][hh * 4 + e], a);
                sc[k] = a * 0.5f;
                mx = fmaxf(mx, sc[k]);
            }
            float sum = 0.f;
            #pragma unroll
            for (int k = 0; k < 16; ++k) { sc[k] = __expf(sc[k] - mx); sum += sc[k]; }
            const float inv = 1.0f / sum;
            #pragma unroll
            for (int e = 0; e < 4; ++e) {
                float a = 0.f;
                #pragma unroll
                for (int k = 0; k < 16; ++k) a = fmaf(sc[k], sV[k][hh * 4 + e], a);
                sO[q][hh * 4 + e] = a * inv;
            }
        }
        __syncthreads();   // b3
        // ---- O projection + residual ----
        #pragma unroll
        for (int it = 0; it < 2; ++it) {
            const int idx = tid + 256 * it, s = idx >> 5, j = idx & 31;
            float acc = sBo[j];
            #pragma unroll
            for (int k = 0; k < 32; ++k) acc = fmaf(sO[s][k], sWo[k * 32 + j], acc);
            sT[s][j] = sZ[s][j] + acc;
        }
        __syncthreads();   // b4
        // ---- LN1: 16-lane butterfly, stats+apply fused ----
        {
            const int s = tid >> 4, g = tid & 15;
            const float v0 = sT[s][g], v1 = sT[s][g + 16];
            float sum = v0 + v1, sq = v0 * v0 + v1 * v1;
            #pragma unroll
            for (int off = 8; off > 0; off >>= 1) {
                sum += __shfl_xor(sum, off);
                sq  += __shfl_xor(sq, off);
            }
            const float mu = sum * (1.0f / 32.0f);
            const float rs = rsqrtf(sq * (1.0f / 32.0f) - mu * mu + 1e-5f);
            sZ[s][g]      = (v0 - mu) * rs * sL1g[g]      + sL1b[g];
            sZ[s][g + 16] = (v1 - mu) * rs * sL1g[g + 16] + sL1b[g + 16];
        }
        __syncthreads();   // b5
        // ---- FFN1 + gelu (fast tanh via expf) ----
        #pragma unroll
        for (int it = 0; it < 8; ++it) {
            const int idx = tid + 256 * it, s = idx >> 7, f = idx & 127;
            float acc = sB1[f];
            #pragma unroll
            for (int k = 0; k < 32; ++k) acc = fmaf(sZ[s][k], sW1[k * 128 + f], acc);
            const float c = acc;
            const float a2 = 1.5957691216057308f * (c + 0.044715f * c * c * c);  // 2*sqrt(2/pi)*(...)
            const float e = __expf(a2);
            const float th = 1.0f - 2.0f / (e + 1.0f);
            sH[s][f] = 0.5f * c * (1.0f + th);
        }
        __syncthreads();   // b6
        // ---- FFN2 + residual (LDS, unrolled) ----
        #pragma unroll
        for (int it = 0; it < 2; ++it) {
            const int idx = tid + 256 * it, s = idx >> 5, j = idx & 31;
            float acc = sB2[j];
            #pragma unroll 16
            for (int k = 0; k < 128; ++k) acc = fmaf(sH[s][k], sW2[k * 32 + j], acc);
            sT[s][j] = sZ[s][j] + acc;
        }
        __syncthreads();   // b7
        // ---- LN2 ----
        {
            const int s = tid >> 4, g = tid & 15;
            const float v0 = sT[s][g], v1 = sT[s][g + 16];
            float sum = v0 + v1, sq = v0 * v0 + v1 * v1;
            #pragma unroll
            for (int off = 8; off > 0; off >>= 1) {
                sum += __shfl_xor(sum, off);
                sq  += __shfl_xor(sq, off);
            }
            const float mu = sum * (1.0f / 32.0f);
            const float rs = rsqrtf(sq * (1.0f / 32.0f) - mu * mu + 1e-5f);
            sZ[s][g]      = (v0 - mu) * rs * sL2g[g]      + sL2b[g];
            sZ[s][g + 16] = (v1 - mu) * rs * sL2g[g + 16] + sL2b[g + 16];
        }
        // no barrier here: next-layer staging touches only sW*/sB*; b1 syncs sZ
    }
    __syncthreads();
    // ---- final LN (each thread owns the same 2 elements it wrote in LN2)
    //      + transposed write into zf[j], j = r*16 + i  (sZ[i][r]) ----
    {
        const int s = tid >> 4, g = tid & 15;
        const float v0 = sZ[s][g], v1 = sZ[s][g + 16];
        float sum = v0 + v1, sq = v0 * v0 + v1 * v1;
        #pragma unroll
        for (int off = 8; off > 0; off >>= 1) {
            sum += __shfl_xor(sum, off);
            sq  += __shfl_xor(sq, off);
        }
        const float mu = sum * (1.0f / 32.0f);
        const float rs = rsqrtf(sq * (1.0f / 32.0f) - mu * mu + 1e-5f);
        sZf[g * 16 + s]        = (v0 - mu) * rs * ln_f_g[g]      + ln_f_b[g];
        sZf[(g + 16) * 16 + s] = (v1 - mu) * rs * ln_f_g[g + 16] + ln_f_b[g + 16];
    }
    __syncthreads();
    // ---- head: out[o] = b_lin[o] + sum_j zf[j] * W_lin[j*96+o]; 2-way j-split ----
    if (tid < 192) {
        const int half = tid / 96, o = tid % 96;
        const int j0 = half * 256;
        float acc = 0.f;
        #pragma unroll 8
        for (int j = 0; j < 256; ++j)
            acc = fmaf(sZf[j0 + j], W_lin[(j0 + j) * 96 + o], acc);
        sPart[half][o] = acc;
    }
    __syncthreads();
    if (tid < 96)
        out[((n >> 5) * 96 + tid) * 32 + (n & 31)] = sPart[0][tid] + sPart[1][tid] + b_lin[tid];
}

// ---------------------------------------------------------------------------
extern "C" void kernel_launch(void* const* d_in, const int* in_sizes, int n_in,
                              void* d_out, int out_size, void* d_ws, size_t ws_size,
                              hipStream_t stream) {
    const float* x       = (const float*)d_in[0];
    const float* x_mark  = (const float*)d_in[1];
    const float* x_mask  = (const float*)d_in[2];
    const float* Wq      = (const float*)d_in[3];
    const float* Wk      = (const float*)d_in[4];
    const float* W_out   = (const float*)d_in[5];
    const float* b_out   = (const float*)d_in[6];
    const float* f_Wq    = (const float*)d_in[7];
    const float* f_Wk    = (const float*)d_in[8];
    const float* f_Wv    = (const float*)d_in[9];
    const float* f_Wo    = (const float*)d_in[10];
    const float* f_bq    = (const float*)d_in[11];
    const float* f_bk    = (const float*)d_in[12];
    const float* f_bv    = (const float*)d_in[13];
    const float* f_bo    = (const float*)d_in[14];
    const float* f_ln1_g = (const float*)d_in[15];
    const float* f_ln1_b = (const float*)d_in[16];
    const float* f_W1    = (const float*)d_in[17];
    const float* f_b1    = (const float*)d_in[18];
    const float* f_W2    = (const float*)d_in[19];
    const float* f_b2    = (const float*)d_in[20];
    const float* f_ln2_g = (const float*)d_in[21];
    const float* f_ln2_b = (const float*)d_in[22];
    const float* ln_f_g  = (const float*)d_in[23];
    const float* ln_f_b  = (const float*)d_in[24];
    const float* W_lin   = (const float*)d_in[25];
    const float* b_lin   = (const float*)d_in[26];

    float* ws = (float*)d_ws;
    float* Kmat      = ws;                      // 4096*128 = 524288
    float* Qall      = ws + 524288;             // 512*128  = 65536
    unsigned* obsB   = (unsigned*)(ws + 589824);// 4096 words
    float* attn      = ws + 593920;             // 16*8*32*128 = 524288
    float* zbuf      = ws + 1118208;            // 256*16*32 = 131072   (total ~5.0 MB)

    k_embed_mm<<<1152, 256, 0, stream>>>(x_mark, Wk, Wq, Kmat, Qall);
    k_obsbits<<<512, 256, 0, stream>>>(x_mask, obsB);
    k_patch_attn<<<512, 256, 0, stream>>>(x, x_mark, obsB, Kmat, Qall, attn);
    k_reprs<<<128, 256, 0, stream>>>(attn, W_out, b_out, zbuf);
    k_former<<<256, 256, 0, stream>>>(zbuf,
        f_Wq, f_Wk, f_Wv, f_Wo, f_bq, f_bk, f_bv, f_bo,
        f_ln1_g, f_ln1_b, f_W1, f_b1, f_W2, f_b2, f_ln2_g, f_ln2_b,
        ln_f_g, ln_f_b, W_lin, b_lin, (float*)d_out);
}

// Round 3
// 77.445 us; speedup vs baseline: 2.2794x; 1.6891x over previous
//
#include <hip/hip_runtime.h>
#include <math.h>

// Model_78271484002488: B=8, L=512, D=32, N_PATCHES=16, N_REF=32, LAT=128, HM=4,
// FH=8, NL=3, FF=128, PRED=96.  All f32.

#define ISQ32 0.17677669529663687f   // 1/sqrt(32)
#define C128  (-0.07195578415606394f)  // -ln(1e4)/128
#define C32   (-0.28782313662425575f)  // -ln(1e4)/32

// ---------------------------------------------------------------------------
// K0 (merged): blocks [0,1152): time-embed matvec -> Kmat / Qall
//              blocks [1152,1664): obsBits via ballot
__global__ void k_embed_mm(const float* __restrict__ x_mark,
                           const float* __restrict__ Wk,
                           const float* __restrict__ Wq,
                           const float* __restrict__ x_mask,
                           float* __restrict__ Kmat,
                           float* __restrict__ Qall,
                           unsigned* __restrict__ obsBits) {
    __shared__ float sTe[4][128];
    if (blockIdx.x >= 1152) {
        const int gt = (blockIdx.x - 1152) * 256 + threadIdx.x;
        const int w = gt >> 6, lane = gt & 63;
        const int bl = w * 2 + (lane >> 5);
        const int d = lane & 31;
        const unsigned long long mm = __ballot(x_mask[bl * 32 + d] > 0.0f);
        if (lane == 0)  obsBits[w * 2]     = (unsigned)(mm & 0xffffffffull);
        if (lane == 32) obsBits[w * 2 + 1] = (unsigned)(mm >> 32);
        return;
    }
    const int wave = threadIdx.x >> 6;
    const int lane = threadIdx.x & 63;
    const int row = blockIdx.x * 4 + wave;
    float t;
    const float* W;
    float* outp;
    if (row < 4096) {
        t = x_mark[row];
        W = Wk;
        outp = Kmat + row * 128;
    } else {
        const int qr = row - 4096;
        t = (float)qr * (512.0f / 511.0f);
        W = Wq;
        outp = Qall + qr * 128;
    }
    const float dv = expf((float)(2 * lane) * C128);
    const float ang = t * dv;
    sTe[wave][2 * lane]     = sinf(ang);
    sTe[wave][2 * lane + 1] = cosf(ang);
    __syncthreads();
    float a0 = 0.f, a1 = 0.f;
    #pragma unroll 8
    for (int k = 0; k < 128; ++k) {
        const float te = sTe[wave][k];
        a0 = fmaf(te, W[k * 128 + lane], a0);
        a1 = fmaf(te, W[k * 128 + lane + 64], a1);
    }
    outp[lane] = a0;
    outp[lane + 64] = a1;
}

// ---------------------------------------------------------------------------
// K1: fused patch attention, range-based.  block = (i,b,h); 256 threads.
// t sorted => in-patch l's are contiguous [lo,hi].  Fast path stages only the
// NA active rows; slow fallback (never hit on random data) is exact.
__launch_bounds__(256)
__global__ void k_patch_attn(const float* __restrict__ x,
                             const float* __restrict__ x_mark,
                             const unsigned* __restrict__ obsBits,
                             const float* __restrict__ Kmat,
                             const float* __restrict__ Qall,
                             float* __restrict__ attn) {
    __shared__ float sQ[32][36];
    __shared__ float sK[96][36];
    __shared__ float sX[96][36];
    __shared__ float sS[32][100];
    __shared__ unsigned sBits[96];
    __shared__ int sLo, sHi;
    __shared__ unsigned sAV;
    const int tid = threadIdx.x;
    const int h = blockIdx.x & 3;
    const int b = (blockIdx.x >> 2) & 7;
    const int i = blockIdx.x >> 5;
    const float e0 = 32.0f * (float)i, e1 = 32.0f * (float)(i + 1);
    if (tid == 0) { sLo = 512; sHi = -1; sAV = 0u; }
    __syncthreads();
    // load Q (32 refs x 32 dims, h slice)
    #pragma unroll
    for (int k = 0; k < 4; ++k) {
        const int idx = tid + 256 * k;
        sQ[idx >> 5][idx & 31] = Qall[(i * 32 + (idx >> 5)) * 128 + h * 32 + (idx & 31)];
    }
    // range find + av (OR of obs bits over in-range l)
    {
        int mylo = 512, myhi = -1;
        unsigned mybits = 0u;
        #pragma unroll
        for (int k = 0; k < 2; ++k) {
            const int l = tid + 256 * k;
            const float t = x_mark[b * 512 + l];
            if (t >= e0 && t <= e1) {
                mylo = min(mylo, l);
                myhi = max(myhi, l);
                mybits |= obsBits[b * 512 + l];
            }
        }
        #pragma unroll
        for (int off = 32; off > 0; off >>= 1) {
            mylo = min(mylo, __shfl_xor(mylo, off));
            myhi = max(myhi, __shfl_xor(myhi, off));
            mybits |= __shfl_xor(mybits, off);
        }
        if ((tid & 63) == 0) {
            atomicMin(&sLo, mylo);
            atomicMax(&sHi, myhi);
            atomicOr(&sAV, mybits);
        }
    }
    __syncthreads();
    const int lo = sLo, hi = sHi;
    const int NA = hi - lo + 1;
    const unsigned av = sAV;
    const int r = tid >> 3, dg = tid & 7;   // 32 r-groups x 8 lanes

    if (NA >= 1 && NA <= 96 && av == 0xffffffffu) {
        // ------------------------------ fast path ------------------------------
        if (tid < NA) sBits[tid] = obsBits[b * 512 + lo + tid];
        for (int idx = tid; idx < NA * 32; idx += 256) {
            const int ll = idx >> 5, c = idx & 31;
            sK[ll][c] = Kmat[(b * 512 + lo + ll) * 128 + h * 32 + c];
            sX[ll][c] = x[(b * 512 + lo + ll) * 32 + c];
        }
        __syncthreads();
        // scores (dense 32 x NA) + group rowmax
        float m = -1e30f;
        for (int ll = dg; ll < NA; ll += 8) {
            float p0 = 0.f, p1 = 0.f, p2 = 0.f, p3 = 0.f;
            #pragma unroll
            for (int e = 0; e < 32; e += 4) {
                p0 = fmaf(sQ[r][e],     sK[ll][e],     p0);
                p1 = fmaf(sQ[r][e + 1], sK[ll][e + 1], p1);
                p2 = fmaf(sQ[r][e + 2], sK[ll][e + 2], p2);
                p3 = fmaf(sQ[r][e + 3], sK[ll][e + 3], p3);
            }
            const float s = (p0 + p1 + p2 + p3) * ISQ32;
            sS[r][ll] = s;
            m = fmaxf(m, s);
        }
        #pragma unroll
        for (int off = 4; off > 0; off >>= 1) m = fmaxf(m, __shfl_xor(m, off));
        for (int ll = dg; ll < NA; ll += 8) sS[r][ll] = __expf(sS[r][ll] - m);
        __syncthreads();
        // masked weighted sums over the NA active rows (effN == effD == bits)
        float num0 = 0.f, num1 = 0.f, num2 = 0.f, num3 = 0.f;
        float den0 = 0.f, den1 = 0.f, den2 = 0.f, den3 = 0.f;
        for (int ll = 0; ll < NA; ++ll) {
            const float e = sS[r][ll];
            const unsigned bits = sBits[ll];
            if ((bits >> dg) & 1u)        { den0 += e; num0 = fmaf(e, sX[ll][dg],      num0); }
            if ((bits >> (dg + 8)) & 1u)  { den1 += e; num1 = fmaf(e, sX[ll][dg + 8],  num1); }
            if ((bits >> (dg + 16)) & 1u) { den2 += e; num2 = fmaf(e, sX[ll][dg + 16], num2); }
            if ((bits >> (dg + 24)) & 1u) { den3 += e; num3 = fmaf(e, sX[ll][dg + 24], num3); }
        }
        float* ap = attn + ((i * 8 + b) * 32 + r) * 128 + h * 32;
        ap[dg]      = num0 / den0;
        ap[dg + 8]  = num1 / den1;
        ap[dg + 16] = num2 / den2;
        ap[dg + 24] = num3 / den3;
    } else {
        // --------------- slow exact fallback (practically never runs) ---------------
        // online softmax per (r, dg); effD = (in_range ? bits : 0) | ~av
        float m = -1e30f;
        float num[4] = {0.f, 0.f, 0.f, 0.f}, den[4] = {0.f, 0.f, 0.f, 0.f};
        for (int l = 0; l < 512; ++l) {
            const float t = x_mark[b * 512 + l];
            const unsigned bits = obsBits[b * 512 + l];
            const bool inr = (t >= e0 && t <= e1);
            const unsigned effD = (inr ? bits : 0u) | ~av;
            if (effD == 0u) continue;
            const unsigned effN = effD & bits;
            const float* Kp = Kmat + (b * 512 + l) * 128 + h * 32;
            float a = 0.f;
            #pragma unroll
            for (int e2 = 0; e2 < 32; ++e2) a = fmaf(sQ[r][e2], Kp[e2], a);
            const float s = a * ISQ32;
            float eNew;
            if (s > m) {
                const float scale = __expf(m - s);
                #pragma unroll
                for (int j = 0; j < 4; ++j) { den[j] *= scale; num[j] *= scale; }
                m = s;
                eNew = 1.0f;
            } else {
                eNew = __expf(s - m);
            }
            const float* xp = x + (b * 512 + l) * 32;
            #pragma unroll
            for (int j = 0; j < 4; ++j) {
                const int d = dg + 8 * j;
                if ((effD >> d) & 1u) den[j] += eNew;
                if ((effN >> d) & 1u) num[j] = fmaf(eNew, xp[d], num[j]);
            }
        }
        float* ap = attn + ((i * 8 + b) * 32 + r) * 128 + h * 32;
        #pragma unroll
        for (int j = 0; j < 4; ++j) ap[dg + 8 * j] = num[j] / den[j];
    }
}

// ---------------------------------------------------------------------------
// K2: reprs = attn(B,32,128) @ W_out + b_out;  z[(b*32+d)][i][r] = reprs + te16(i,r)
__global__ void k_reprs(const float* __restrict__ attn,
                        const float* __restrict__ W_out,
                        const float* __restrict__ b_out,
                        float* __restrict__ z) {
    __shared__ float sA[32][129];
    const int tid = threadIdx.x;
    const int b = blockIdx.x & 7;
    const int i = blockIdx.x >> 3;
    #pragma unroll
    for (int k = 0; k < 16; ++k) {
        const int idx = tid + 256 * k;
        sA[idx >> 7][idx & 127] = attn[(i * 8 + b) * 4096 + idx];
    }
    __syncthreads();
    const int r = tid & 31, dgrp = tid >> 5;
    float acc0 = 0.f, acc1 = 0.f, acc2 = 0.f, acc3 = 0.f;
    #pragma unroll 8
    for (int k = 0; k < 128; ++k) {
        const float a = sA[r][k];
        acc0 = fmaf(a, W_out[k * 32 + dgrp],      acc0);
        acc1 = fmaf(a, W_out[k * 32 + dgrp + 8],  acc1);
        acc2 = fmaf(a, W_out[k * 32 + dgrp + 16], acc2);
        acc3 = fmaf(a, W_out[k * 32 + dgrp + 24], acc3);
    }
    const float dv = expf((float)(2 * (r >> 1)) * C32);
    const float ang = (float)i * dv;
    const float pe = (r & 1) ? cosf(ang) : sinf(ang);
    const int base = i * 32 + r;
    z[(b * 32 + dgrp)      * 512 + base] = acc0 + b_out[dgrp]      + pe;
    z[(b * 32 + dgrp + 8)  * 512 + base] = acc1 + b_out[dgrp + 8]  + pe;
    z[(b * 32 + dgrp + 16) * 512 + base] = acc2 + b_out[dgrp + 16] + pe;
    z[(b * 32 + dgrp + 24) * 512 + base] = acc3 + b_out[dgrp + 24] + pe;
}

// ---------------------------------------------------------------------------
// K3: 3-layer transformer (S=16, dm=32, 8 heads of 4) + final LN + head.
__launch_bounds__(256)
__global__ void k_former(const float* __restrict__ z,
                         const float* __restrict__ f_Wq, const float* __restrict__ f_Wk,
                         const float* __restrict__ f_Wv, const float* __restrict__ f_Wo,
                         const float* __restrict__ f_bq, const float* __restrict__ f_bk,
                         const float* __restrict__ f_bv, const float* __restrict__ f_bo,
                         const float* __restrict__ f_ln1_g, const float* __restrict__ f_ln1_b,
                         const float* __restrict__ f_W1, const float* __restrict__ f_b1,
                         const float* __restrict__ f_W2, const float* __restrict__ f_b2,
                         const float* __restrict__ f_ln2_g, const float* __restrict__ f_ln2_b,
                         const float* __restrict__ ln_f_g, const float* __restrict__ ln_f_b,
                         const float* __restrict__ W_lin, const float* __restrict__ b_lin,
                         float* __restrict__ out) {
    __shared__ float sZ[16][33], sQ[16][33], sK[16][33], sV[16][33], sO[16][33], sT[16][33];
    __shared__ float sH[16][129];
    __shared__ float sWq[1024], sWk[1024], sWv[1024], sWo[1024];
    __shared__ float sW1[4096], sW2[4096];
    __shared__ float sBq[32], sBk[32], sBv[32], sBo[32], sB1[128], sB2[32];
    __shared__ float sL1g[32], sL1b[32], sL2g[32], sL2b[32];
    __shared__ float sZf[512];
    __shared__ float sPart[2][96];
    const int tid = threadIdx.x;
    const int n = blockIdx.x;
    #pragma unroll
    for (int k = 0; k < 2; ++k) {
        const int idx = tid + 256 * k;
        sZ[idx >> 5][idx & 31] = z[n * 512 + idx];
    }
    for (int layer = 0; layer < 3; ++layer) {
        ((float4*)sWq)[tid] = ((const float4*)(f_Wq + layer * 1024))[tid];
        ((float4*)sWk)[tid] = ((const float4*)(f_Wk + layer * 1024))[tid];
        ((float4*)sWv)[tid] = ((const float4*)(f_Wv + layer * 1024))[tid];
        ((float4*)sWo)[tid] = ((const float4*)(f_Wo + layer * 1024))[tid];
        #pragma unroll
        for (int k2 = 0; k2 < 4; ++k2) {
            ((float4*)sW1)[tid + 256 * k2] = ((const float4*)(f_W1 + layer * 4096))[tid + 256 * k2];
            ((float4*)sW2)[tid + 256 * k2] = ((const float4*)(f_W2 + layer * 4096))[tid + 256 * k2];
        }
        {
            const int j = tid & 31;
            switch (tid >> 5) {
                case 0: sBq[j]  = f_bq[layer * 32 + j];    break;
                case 1: sBk[j]  = f_bk[layer * 32 + j];    break;
                case 2: sBv[j]  = f_bv[layer * 32 + j];    break;
                case 3: sBo[j]  = f_bo[layer * 32 + j];    break;
                case 4: sB2[j]  = f_b2[layer * 32 + j];    break;
                case 5: sL1g[j] = f_ln1_g[layer * 32 + j]; break;
                case 6: sL1b[j] = f_ln1_b[layer * 32 + j]; break;
                case 7: sL2g[j] = f_ln2_g[layer * 32 + j]; break;
            }
            if (tid < 128) sB1[tid] = f_b1[layer * 128 + tid];
            else if (tid < 160) sL2b[tid - 128] = f_ln2_b[layer * 32 + (tid - 128)];
        }
        __syncthreads();
        #pragma unroll
        for (int it = 0; it < 6; ++it) {
            const int idx = tid + 256 * it;
            const int which = idx >> 9, rem = idx & 511, s = rem >> 5, j = rem & 31;
            const float* W  = (which == 0) ? sWq : ((which == 1) ? sWk : sWv);
            const float* bb = (which == 0) ? sBq : ((which == 1) ? sBk : sBv);
            float acc = bb[j];
            #pragma unroll
            for (int k = 0; k < 32; ++k) acc = fmaf(sZ[s][k], W[k * 32 + j], acc);
            if (which == 0) sQ[s][j] = acc;
            else if (which == 1) sK[s][j] = acc;
            else sV[s][j] = acc;
        }
        __syncthreads();
        if (tid < 128) {
            const int hh = tid >> 4, q = tid & 15;
            float sc[16];
            float mx = -1e30f;
            #pragma unroll
            for (int k = 0; k < 16; ++k) {
                float a = 0.f;
                #pragma unroll
                for (int e = 0; e < 4; ++e) a = fmaf(sQ[q][hh * 4 + e], sK[k][hh * 4 + e], a);
                sc[k] = a * 0.5f;
                mx = fmaxf(mx, sc[k]);
            }
            float sum = 0.f;
            #pragma unroll
            for (int k = 0; k < 16; ++k) { sc[k] = __expf(sc[k] - mx); sum += sc[k]; }
            const float inv = 1.0f / sum;
            #pragma unroll
            for (int e = 0; e < 4; ++e) {
                float a = 0.f;
                #pragma unroll
                for (int k = 0; k < 16; ++k) a = fmaf(sc[k], sV[k][hh * 4 + e], a);
                sO[q][hh * 4 + e] = a * inv;
            }
        }
        __syncthreads();
        #pragma unroll
        for (int it = 0; it < 2; ++it) {
            const int idx = tid + 256 * it, s = idx >> 5, j = idx & 31;
            float acc = sBo[j];
            #pragma unroll
            for (int k = 0; k < 32; ++k) acc = fmaf(sO[s][k], sWo[k * 32 + j], acc);
            sT[s][j] = sZ[s][j] + acc;
        }
        __syncthreads();
        {
            const int s = tid >> 4, g = tid & 15;
            const float v0 = sT[s][g], v1 = sT[s][g + 16];
            float sum = v0 + v1, sq = v0 * v0 + v1 * v1;
            #pragma unroll
            for (int off = 8; off > 0; off >>= 1) {
                sum += __shfl_xor(sum, off);
                sq  += __shfl_xor(sq, off);
            }
            const float mu = sum * (1.0f / 32.0f);
            const float rs = rsqrtf(sq * (1.0f / 32.0f) - mu * mu + 1e-5f);
            sZ[s][g]      = (v0 - mu) * rs * sL1g[g]      + sL1b[g];
            sZ[s][g + 16] = (v1 - mu) * rs * sL1g[g + 16] + sL1b[g + 16];
        }
        __syncthreads();
        #pragma unroll
        for (int it = 0; it < 8; ++it) {
            const int idx = tid + 256 * it, s = idx >> 7, f = idx & 127;
            float acc = sB1[f];
            #pragma unroll
            for (int k = 0; k < 32; ++k) acc = fmaf(sZ[s][k], sW1[k * 128 + f], acc);
            const float c = acc;
            const float a2 = 1.5957691216057308f * (c + 0.044715f * c * c * c);
            const float e = __expf(a2);
            const float th = 1.0f - 2.0f / (e + 1.0f);
            sH[s][f] = 0.5f * c * (1.0f + th);
        }
        __syncthreads();
        #pragma unroll
        for (int it = 0; it < 2; ++it) {
            const int idx = tid + 256 * it, s = idx >> 5, j = idx & 31;
            float acc = sB2[j];
            #pragma unroll 16
            for (int k = 0; k < 128; ++k) acc = fmaf(sH[s][k], sW2[k * 32 + j], acc);
            sT[s][j] = sZ[s][j] + acc;
        }
        __syncthreads();
        {
            const int s = tid >> 4, g = tid & 15;
            const float v0 = sT[s][g], v1 = sT[s][g + 16];
            float sum = v0 + v1, sq = v0 * v0 + v1 * v1;
            #pragma unroll
            for (int off = 8; off > 0; off >>= 1) {
                sum += __shfl_xor(sum, off);
                sq  += __shfl_xor(sq, off);
            }
            const float mu = sum * (1.0f / 32.0f);
            const float rs = rsqrtf(sq * (1.0f / 32.0f) - mu * mu + 1e-5f);
            sZ[s][g]      = (v0 - mu) * rs * sL2g[g]      + sL2b[g];
            sZ[s][g + 16] = (v1 - mu) * rs * sL2g[g + 16] + sL2b[g + 16];
        }
    }
    __syncthreads();
    {
        const int s = tid >> 4, g = tid & 15;
        const float v0 = sZ[s][g], v1 = sZ[s][g + 16];
        float sum = v0 + v1, sq = v0 * v0 + v1 * v1;
        #pragma unroll
        for (int off = 8; off > 0; off >>= 1) {
            sum += __shfl_xor(sum, off);
            sq  += __shfl_xor(sq, off);
        }
        const float mu = sum * (1.0f / 32.0f);
        const float rs = rsqrtf(sq * (1.0f / 32.0f) - mu * mu + 1e-5f);
        sZf[g * 16 + s]        = (v0 - mu) * rs * ln_f_g[g]      + ln_f_b[g];
        sZf[(g + 16) * 16 + s] = (v1 - mu) * rs * ln_f_g[g + 16] + ln_f_b[g + 16];
    }
    __syncthreads();
    if (tid < 192) {
        const int half = tid / 96, o = tid % 96;
        const int j0 = half * 256;
        float acc = 0.f;
        #pragma unroll 8
        for (int j = 0; j < 256; ++j)
            acc = fmaf(sZf[j0 + j], W_lin[(j0 + j) * 96 + o], acc);
        sPart[half][o] = acc;
    }
    __syncthreads();
    if (tid < 96)
        out[((n >> 5) * 96 + tid) * 32 + (n & 31)] = sPart[0][tid] + sPart[1][tid] + b_lin[tid];
}

// ---------------------------------------------------------------------------
extern "C" void kernel_launch(void* const* d_in, const int* in_sizes, int n_in,
                              void* d_out, int out_size, void* d_ws, size_t ws_size,
                              hipStream_t stream) {
    const float* x       = (const float*)d_in[0];
    const float* x_mark  = (const float*)d_in[1];
    const float* x_mask  = (const float*)d_in[2];
    const float* Wq      = (const float*)d_in[3];
    const float* Wk      = (const float*)d_in[4];
    const float* W_out   = (const float*)d_in[5];
    const float* b_out   = (const float*)d_in[6];
    const float* f_Wq    = (const float*)d_in[7];
    const float* f_Wk    = (const float*)d_in[8];
    const float* f_Wv    = (const float*)d_in[9];
    const float* f_Wo    = (const float*)d_in[10];
    const float* f_bq    = (const float*)d_in[11];
    const float* f_bk    = (const float*)d_in[12];
    const float* f_bv    = (const float*)d_in[13];
    const float* f_bo    = (const float*)d_in[14];
    const float* f_ln1_g = (const float*)d_in[15];
    const float* f_ln1_b = (const float*)d_in[16];
    const float* f_W1    = (const float*)d_in[17];
    const float* f_b1    = (const float*)d_in[18];
    const float* f_W2    = (const float*)d_in[19];
    const float* f_b2    = (const float*)d_in[20];
    const float* f_ln2_g = (const float*)d_in[21];
    const float* f_ln2_b = (const float*)d_in[22];
    const float* ln_f_g  = (const float*)d_in[23];
    const float* ln_f_b  = (const float*)d_in[24];
    const float* W_lin   = (const float*)d_in[25];
    const float* b_lin   = (const float*)d_in[26];

    float* ws = (float*)d_ws;
    float* Kmat      = ws;                      // 4096*128 = 524288
    float* Qall      = ws + 524288;             // 512*128  = 65536
    unsigned* obsB   = (unsigned*)(ws + 589824);// 4096 words
    float* attn      = ws + 593920;             // 16*8*32*128 = 524288
    float* zbuf      = ws + 1118208;            // 256*16*32 = 131072   (total ~5.0 MB)

    k_embed_mm<<<1664, 256, 0, stream>>>(x_mark, Wk, Wq, x_mask, Kmat, Qall, obsB);
    k_patch_attn<<<512, 256, 0, stream>>>(x, x_mark, obsB, Kmat, Qall, attn);
    k_reprs<<<128, 256, 0, stream>>>(attn, W_out, b_out, zbuf);
    k_former<<<256, 256, 0, stream>>>(zbuf,
        f_Wq, f_Wk, f_Wv, f_Wo, f_bq, f_bk, f_bv, f_bo,
        f_ln1_g, f_ln1_b, f_W1, f_b1, f_W2, f_b2, f_ln2_g, f_ln2_b,
        ln_f_g, ln_f_b, W_lin, b_lin, (float*)d_out);
}

// Round 4
// 70.359 us; speedup vs baseline: 2.5090x; 1.1007x over previous
//
#include <hip/hip_runtime.h>
#include <math.h>

// Model_78271484002488: B=8, L=512, D=32, N_PATCHES=16, N_REF=32, LAT=128, HM=4,
// FH=8, NL=3, FF=128, PRED=96.  All f32.

#define ISQ32 0.17677669529663687f   // 1/sqrt(32)
#define C128  (-0.07195578415606394f)  // -ln(1e4)/128
#define C32   (-0.28782313662425575f)  // -ln(1e4)/32

// ---------------------------------------------------------------------------
// K0 (merged): blocks [0,1152): time-embed matvec -> Kmat / Qall
//              blocks [1152,1664): obsBits via ballot
__global__ void k_embed_mm(const float* __restrict__ x_mark,
                           const float* __restrict__ Wk,
                           const float* __restrict__ Wq,
                           const float* __restrict__ x_mask,
                           float* __restrict__ Kmat,
                           float* __restrict__ Qall,
                           unsigned* __restrict__ obsBits) {
    __shared__ float sTe[4][128];
    if (blockIdx.x >= 1152) {
        const int gt = (blockIdx.x - 1152) * 256 + threadIdx.x;
        const int w = gt >> 6, lane = gt & 63;
        const int bl = w * 2 + (lane >> 5);
        const int d = lane & 31;
        const unsigned long long mm = __ballot(x_mask[bl * 32 + d] > 0.0f);
        if (lane == 0)  obsBits[w * 2]     = (unsigned)(mm & 0xffffffffull);
        if (lane == 32) obsBits[w * 2 + 1] = (unsigned)(mm >> 32);
        return;
    }
    const int wave = threadIdx.x >> 6;
    const int lane = threadIdx.x & 63;
    const int row = blockIdx.x * 4 + wave;
    float t;
    const float* W;
    float* outp;
    if (row < 4096) {
        t = x_mark[row];
        W = Wk;
        outp = Kmat + row * 128;
    } else {
        const int qr = row - 4096;
        t = (float)qr * (512.0f / 511.0f);
        W = Wq;
        outp = Qall + qr * 128;
    }
    const float dv = expf((float)(2 * lane) * C128);
    const float ang = t * dv;
    sTe[wave][2 * lane]     = sinf(ang);
    sTe[wave][2 * lane + 1] = cosf(ang);
    __syncthreads();
    float a0 = 0.f, a1 = 0.f;
    #pragma unroll 8
    for (int k = 0; k < 128; ++k) {
        const float te = sTe[wave][k];
        a0 = fmaf(te, W[k * 128 + lane], a0);
        a1 = fmaf(te, W[k * 128 + lane + 64], a1);
    }
    outp[lane] = a0;
    outp[lane + 64] = a1;
}

// ---------------------------------------------------------------------------
// K1: fused patch attention, range-based.  block = (i,b,h); 256 threads.
__launch_bounds__(256)
__global__ void k_patch_attn(const float* __restrict__ x,
                             const float* __restrict__ x_mark,
                             const unsigned* __restrict__ obsBits,
                             const float* __restrict__ Kmat,
                             const float* __restrict__ Qall,
                             float* __restrict__ attn) {
    __shared__ float sQ[32][36];
    __shared__ float sK[96][36];
    __shared__ float sX[96][36];
    __shared__ float sS[32][100];
    __shared__ unsigned sBits[96];
    __shared__ int sLo, sHi;
    __shared__ unsigned sAV;
    const int tid = threadIdx.x;
    const int h = blockIdx.x & 3;
    const int b = (blockIdx.x >> 2) & 7;
    const int i = blockIdx.x >> 5;
    const float e0 = 32.0f * (float)i, e1 = 32.0f * (float)(i + 1);
    if (tid == 0) { sLo = 512; sHi = -1; sAV = 0u; }
    __syncthreads();
    #pragma unroll
    for (int k = 0; k < 4; ++k) {
        const int idx = tid + 256 * k;
        sQ[idx >> 5][idx & 31] = Qall[(i * 32 + (idx >> 5)) * 128 + h * 32 + (idx & 31)];
    }
    {
        int mylo = 512, myhi = -1;
        unsigned mybits = 0u;
        #pragma unroll
        for (int k = 0; k < 2; ++k) {
            const int l = tid + 256 * k;
            const float t = x_mark[b * 512 + l];
            if (t >= e0 && t <= e1) {
                mylo = min(mylo, l);
                myhi = max(myhi, l);
                mybits |= obsBits[b * 512 + l];
            }
        }
        #pragma unroll
        for (int off = 32; off > 0; off >>= 1) {
            mylo = min(mylo, __shfl_xor(mylo, off));
            myhi = max(myhi, __shfl_xor(myhi, off));
            mybits |= __shfl_xor(mybits, off);
        }
        if ((tid & 63) == 0) {
            atomicMin(&sLo, mylo);
            atomicMax(&sHi, myhi);
            atomicOr(&sAV, mybits);
        }
    }
    __syncthreads();
    const int lo = sLo, hi = sHi;
    const int NA = hi - lo + 1;
    const unsigned av = sAV;
    const int r = tid >> 3, dg = tid & 7;

    if (NA >= 1 && NA <= 96 && av == 0xffffffffu) {
        if (tid < NA) sBits[tid] = obsBits[b * 512 + lo + tid];
        for (int idx = tid; idx < NA * 32; idx += 256) {
            const int ll = idx >> 5, c = idx & 31;
            sK[ll][c] = Kmat[(b * 512 + lo + ll) * 128 + h * 32 + c];
            sX[ll][c] = x[(b * 512 + lo + ll) * 32 + c];
        }
        __syncthreads();
        float m = -1e30f;
        for (int ll = dg; ll < NA; ll += 8) {
            float p0 = 0.f, p1 = 0.f, p2 = 0.f, p3 = 0.f;
            #pragma unroll
            for (int e = 0; e < 32; e += 4) {
                p0 = fmaf(sQ[r][e],     sK[ll][e],     p0);
                p1 = fmaf(sQ[r][e + 1], sK[ll][e + 1], p1);
                p2 = fmaf(sQ[r][e + 2], sK[ll][e + 2], p2);
                p3 = fmaf(sQ[r][e + 3], sK[ll][e + 3], p3);
            }
            const float s = (p0 + p1 + p2 + p3) * ISQ32;
            sS[r][ll] = s;
            m = fmaxf(m, s);
        }
        #pragma unroll
        for (int off = 4; off > 0; off >>= 1) m = fmaxf(m, __shfl_xor(m, off));
        for (int ll = dg; ll < NA; ll += 8) sS[r][ll] = __expf(sS[r][ll] - m);
        __syncthreads();
        float num0 = 0.f, num1 = 0.f, num2 = 0.f, num3 = 0.f;
        float den0 = 0.f, den1 = 0.f, den2 = 0.f, den3 = 0.f;
        for (int ll = 0; ll < NA; ++ll) {
            const float e = sS[r][ll];
            const unsigned bits = sBits[ll];
            if ((bits >> dg) & 1u)        { den0 += e; num0 = fmaf(e, sX[ll][dg],      num0); }
            if ((bits >> (dg + 8)) & 1u)  { den1 += e; num1 = fmaf(e, sX[ll][dg + 8],  num1); }
            if ((bits >> (dg + 16)) & 1u) { den2 += e; num2 = fmaf(e, sX[ll][dg + 16], num2); }
            if ((bits >> (dg + 24)) & 1u) { den3 += e; num3 = fmaf(e, sX[ll][dg + 24], num3); }
        }
        float* ap = attn + ((i * 8 + b) * 32 + r) * 128 + h * 32;
        ap[dg]      = num0 / den0;
        ap[dg + 8]  = num1 / den1;
        ap[dg + 16] = num2 / den2;
        ap[dg + 24] = num3 / den3;
    } else {
        float m = -1e30f;
        float num[4] = {0.f, 0.f, 0.f, 0.f}, den[4] = {0.f, 0.f, 0.f, 0.f};
        for (int l = 0; l < 512; ++l) {
            const float t = x_mark[b * 512 + l];
            const unsigned bits = obsBits[b * 512 + l];
            const bool inr = (t >= e0 && t <= e1);
            const unsigned effD = (inr ? bits : 0u) | ~av;
            if (effD == 0u) continue;
            const unsigned effN = effD & bits;
            const float* Kp = Kmat + (b * 512 + l) * 128 + h * 32;
            float a = 0.f;
            #pragma unroll
            for (int e2 = 0; e2 < 32; ++e2) a = fmaf(sQ[r][e2], Kp[e2], a);
            const float s = a * ISQ32;
            float eNew;
            if (s > m) {
                const float scale = __expf(m - s);
                #pragma unroll
                for (int j = 0; j < 4; ++j) { den[j] *= scale; num[j] *= scale; }
                m = s;
                eNew = 1.0f;
            } else {
                eNew = __expf(s - m);
            }
            const float* xp = x + (b * 512 + l) * 32;
            #pragma unroll
            for (int j = 0; j < 4; ++j) {
                const int d = dg + 8 * j;
                if ((effD >> d) & 1u) den[j] += eNew;
                if ((effN >> d) & 1u) num[j] = fmaf(eNew, xp[d], num[j]);
            }
        }
        float* ap = attn + ((i * 8 + b) * 32 + r) * 128 + h * 32;
        #pragma unroll
        for (int j = 0; j < 4; ++j) ap[dg + 8 * j] = num[j] / den[j];
    }
}

// ---------------------------------------------------------------------------
// K2: reprs = attn(B,32,128) @ W_out + b_out;  z[(b*32+d)][i][r] = reprs + te16(i,r)
__global__ void k_reprs(const float* __restrict__ attn,
                        const float* __restrict__ W_out,
                        const float* __restrict__ b_out,
                        float* __restrict__ z) {
    __shared__ float sA[32][129];
    const int tid = threadIdx.x;
    const int b = blockIdx.x & 7;
    const int i = blockIdx.x >> 3;
    #pragma unroll
    for (int k = 0; k < 16; ++k) {
        const int idx = tid + 256 * k;
        sA[idx >> 7][idx & 127] = attn[(i * 8 + b) * 4096 + idx];
    }
    __syncthreads();
    const int r = tid & 31, dgrp = tid >> 5;
    float acc0 = 0.f, acc1 = 0.f, acc2 = 0.f, acc3 = 0.f;
    #pragma unroll 8
    for (int k = 0; k < 128; ++k) {
        const float a = sA[r][k];
        acc0 = fmaf(a, W_out[k * 32 + dgrp],      acc0);
        acc1 = fmaf(a, W_out[k * 32 + dgrp + 8],  acc1);
        acc2 = fmaf(a, W_out[k * 32 + dgrp + 16], acc2);
        acc3 = fmaf(a, W_out[k * 32 + dgrp + 24], acc3);
    }
    const float dv = expf((float)(2 * (r >> 1)) * C32);
    const float ang = (float)i * dv;
    const float pe = (r & 1) ? cosf(ang) : sinf(ang);
    const int base = i * 32 + r;
    z[(b * 32 + dgrp)      * 512 + base] = acc0 + b_out[dgrp]      + pe;
    z[(b * 32 + dgrp + 8)  * 512 + base] = acc1 + b_out[dgrp + 8]  + pe;
    z[(b * 32 + dgrp + 16) * 512 + base] = acc2 + b_out[dgrp + 16] + pe;
    z[(b * 32 + dgrp + 24) * 512 + base] = acc3 + b_out[dgrp + 24] + pe;
}

// ---------------------------------------------------------------------------
// K3: 3-layer transformer (S=16, dm=32, 8 heads of 4) + final LN + head.
// Weights in REGISTERS (per-thread columns, direct from global/L2); activations
// broadcast from small LDS as float4; residual stream in registers; LN via
// in-wave 32-lane butterflies.
__launch_bounds__(256, 1)
__global__ void k_former(const float* __restrict__ z,
                         const float* __restrict__ f_Wq, const float* __restrict__ f_Wk,
                         const float* __restrict__ f_Wv, const float* __restrict__ f_Wo,
                         const float* __restrict__ f_bq, const float* __restrict__ f_bk,
                         const float* __restrict__ f_bv, const float* __restrict__ f_bo,
                         const float* __restrict__ f_ln1_g, const float* __restrict__ f_ln1_b,
                         const float* __restrict__ f_W1, const float* __restrict__ f_b1,
                         const float* __restrict__ f_W2, const float* __restrict__ f_b2,
                         const float* __restrict__ f_ln2_g, const float* __restrict__ f_ln2_b,
                         const float* __restrict__ ln_f_g, const float* __restrict__ ln_f_b,
                         const float* __restrict__ W_lin, const float* __restrict__ b_lin,
                         float* __restrict__ out) {
    __shared__ float sZ[16][32];               // activations (row=token, col=dm)
    __shared__ float sQ[16][33], sK[16][33], sV[16][33];
    __shared__ float sO[16][32];
    __shared__ float sH[16][128];
    __shared__ float sZf[512];
    __shared__ float sPart[2][96];
    const int tid = threadIdx.x;
    const int n = blockIdx.x;
    const int j = tid & 31, s2 = tid >> 5;     // s2 in [0,8): token pair
    const int sA = s2 * 2, sB = sA + 1;

    // load z: LDS copy + register residual stream for this thread's (sA/sB, j)
    #pragma unroll
    for (int k = 0; k < 2; ++k) {
        const int idx = tid + 256 * k;
        sZ[idx >> 5][idx & 31] = z[n * 512 + idx];
    }
    float zlocA = z[n * 512 + sA * 32 + j];
    float zlocB = z[n * 512 + sB * 32 + j];
    __syncthreads();

    for (int layer = 0; layer < 3; ++layer) {
        const float* Wq = f_Wq + layer * 1024;
        const float* Wk = f_Wk + layer * 1024;
        const float* Wv = f_Wv + layer * 1024;
        const float* Wo = f_Wo + layer * 1024;
        const float* W1 = f_W1 + layer * 4096;
        const float* W2 = f_W2 + layer * 4096;

        // ---- QKV: weight columns in registers, sZ rows broadcast as float4 ----
        {
            float wq[32], wk[32], wv[32];
            #pragma unroll
            for (int k = 0; k < 32; ++k) {
                wq[k] = Wq[k * 32 + j];
                wk[k] = Wk[k * 32 + j];
                wv[k] = Wv[k * 32 + j];
            }
            float qa = f_bq[layer * 32 + j], qb = qa;
            float ka = f_bk[layer * 32 + j], kb = ka;
            float va = f_bv[layer * 32 + j], vb = va;
            const float4* zra = (const float4*)&sZ[sA][0];
            const float4* zrb = (const float4*)&sZ[sB][0];
            #pragma unroll
            for (int k4 = 0; k4 < 8; ++k4) {
                const float4 a = zra[k4], b4 = zrb[k4];
                qa = fmaf(a.x, wq[4*k4], qa);   qa = fmaf(a.y, wq[4*k4+1], qa);
                qa = fmaf(a.z, wq[4*k4+2], qa); qa = fmaf(a.w, wq[4*k4+3], qa);
                qb = fmaf(b4.x, wq[4*k4], qb);   qb = fmaf(b4.y, wq[4*k4+1], qb);
                qb = fmaf(b4.z, wq[4*k4+2], qb); qb = fmaf(b4.w, wq[4*k4+3], qb);
                ka = fmaf(a.x, wk[4*k4], ka);   ka = fmaf(a.y, wk[4*k4+1], ka);
                ka = fmaf(a.z, wk[4*k4+2], ka); ka = fmaf(a.w, wk[4*k4+3], ka);
                kb = fmaf(b4.x, wk[4*k4], kb);   kb = fmaf(b4.y, wk[4*k4+1], kb);
                kb = fmaf(b4.z, wk[4*k4+2], kb); kb = fmaf(b4.w, wk[4*k4+3], kb);
                va = fmaf(a.x, wv[4*k4], va);   va = fmaf(a.y, wv[4*k4+1], va);
                va = fmaf(a.z, wv[4*k4+2], va); va = fmaf(a.w, wv[4*k4+3], va);
                vb = fmaf(b4.x, wv[4*k4], vb);   vb = fmaf(b4.y, wv[4*k4+1], vb);
                vb = fmaf(b4.z, wv[4*k4+2], vb); vb = fmaf(b4.w, wv[4*k4+3], vb);
            }
            sQ[sA][j] = qa; sQ[sB][j] = qb;
            sK[sA][j] = ka; sK[sB][j] = kb;
            sV[sA][j] = va; sV[sB][j] = vb;
        }
        __syncthreads();   // b1
        // ---- attention per (head, q-token) ----
        if (tid < 128) {
            const int hh = tid >> 4, q = tid & 15;
            float sc[16];
            float mx = -1e30f;
            #pragma unroll
            for (int k = 0; k < 16; ++k) {
                float a = 0.f;
                #pragma unroll
                for (int e = 0; e < 4; ++e) a = fmaf(sQ[q][hh * 4 + e], sK[k][hh * 4 + e], a);
                sc[k] = a * 0.5f;
                mx = fmaxf(mx, sc[k]);
            }
            float sum = 0.f;
            #pragma unroll
            for (int k = 0; k < 16; ++k) { sc[k] = __expf(sc[k] - mx); sum += sc[k]; }
            const float inv = 1.0f / sum;
            #pragma unroll
            for (int e = 0; e < 4; ++e) {
                float a = 0.f;
                #pragma unroll
                for (int k = 0; k < 16; ++k) a = fmaf(sc[k], sV[k][hh * 4 + e], a);
                sO[q][hh * 4 + e] = a * inv;
            }
        }
        __syncthreads();   // b2
        // ---- O projection + residual + LN1 (in-wave) ----
        {
            float wo[32];
            #pragma unroll
            for (int k = 0; k < 32; ++k) wo[k] = Wo[k * 32 + j];
            float oa = f_bo[layer * 32 + j], ob = oa;
            const float4* ora = (const float4*)&sO[sA][0];
            const float4* orb = (const float4*)&sO[sB][0];
            #pragma unroll
            for (int k4 = 0; k4 < 8; ++k4) {
                const float4 a = ora[k4], b4 = orb[k4];
                oa = fmaf(a.x, wo[4*k4], oa);   oa = fmaf(a.y, wo[4*k4+1], oa);
                oa = fmaf(a.z, wo[4*k4+2], oa); oa = fmaf(a.w, wo[4*k4+3], oa);
                ob = fmaf(b4.x, wo[4*k4], ob);   ob = fmaf(b4.y, wo[4*k4+1], ob);
                ob = fmaf(b4.z, wo[4*k4+2], ob); ob = fmaf(b4.w, wo[4*k4+3], ob);
            }
            const float tA = zlocA + oa, tB = zlocB + ob;
            float sumA = tA, sqA = tA * tA, sumB = tB, sqB = tB * tB;
            #pragma unroll
            for (int off = 16; off > 0; off >>= 1) {
                sumA += __shfl_xor(sumA, off); sqA += __shfl_xor(sqA, off);
                sumB += __shfl_xor(sumB, off); sqB += __shfl_xor(sqB, off);
            }
            const float muA = sumA * (1.0f / 32.0f);
            const float rsA = rsqrtf(sqA * (1.0f / 32.0f) - muA * muA + 1e-5f);
            const float muB = sumB * (1.0f / 32.0f);
            const float rsB = rsqrtf(sqB * (1.0f / 32.0f) - muB * muB + 1e-5f);
            const float g1 = f_ln1_g[layer * 32 + j], be1 = f_ln1_b[layer * 32 + j];
            zlocA = (tA - muA) * rsA * g1 + be1;
            zlocB = (tB - muB) * rsB * g1 + be1;
            sZ[sA][j] = zlocA;
            sZ[sB][j] = zlocB;
        }
        __syncthreads();   // b3
        // ---- FFN1 + gelu: W1 column in regs, 8 tokens per thread ----
        {
            const int f = tid & 127, sh = tid >> 7;
            float w1c[32];
            #pragma unroll
            for (int k = 0; k < 32; ++k) w1c[k] = W1[k * 128 + f];
            const float b1v = f_b1[layer * 128 + f];
            #pragma unroll
            for (int ss = 0; ss < 8; ++ss) {
                const int s = sh * 8 + ss;
                const float4* zr = (const float4*)&sZ[s][0];
                float acc = b1v;
                #pragma unroll
                for (int k4 = 0; k4 < 8; ++k4) {
                    const float4 a = zr[k4];
                    acc = fmaf(a.x, w1c[4*k4], acc);   acc = fmaf(a.y, w1c[4*k4+1], acc);
                    acc = fmaf(a.z, w1c[4*k4+2], acc); acc = fmaf(a.w, w1c[4*k4+3], acc);
                }
                const float c = acc;
                const float a2 = 1.5957691216057308f * (c + 0.044715f * c * c * c);
                const float e = __expf(a2);
                const float th = 1.0f - 2.0f / (e + 1.0f);
                sH[s][f] = 0.5f * c * (1.0f + th);
            }
        }
        // ---- W2 column prefetch (latency hidden behind barrier + FFN2 entry) ----
        float w2c[128];
        #pragma unroll
        for (int k = 0; k < 128; ++k) w2c[k] = W2[k * 32 + j];
        __syncthreads();   // b4
        // ---- FFN2 + residual + LN2 (in-wave) ----
        {
            float fa = f_b2[layer * 32 + j], fb = fa;
            const float4* hra = (const float4*)&sH[sA][0];
            const float4* hrb = (const float4*)&sH[sB][0];
            #pragma unroll
            for (int k4 = 0; k4 < 32; ++k4) {
                const float4 a = hra[k4], b4 = hrb[k4];
                fa = fmaf(a.x, w2c[4*k4], fa);   fa = fmaf(a.y, w2c[4*k4+1], fa);
                fa = fmaf(a.z, w2c[4*k4+2], fa); fa = fmaf(a.w, w2c[4*k4+3], fa);
                fb = fmaf(b4.x, w2c[4*k4], fb);   fb = fmaf(b4.y, w2c[4*k4+1], fb);
                fb = fmaf(b4.z, w2c[4*k4+2], fb); fb = fmaf(b4.w, w2c[4*k4+3], fb);
            }
            const float tA = zlocA + fa, tB = zlocB + fb;
            float sumA = tA, sqA = tA * tA, sumB = tB, sqB = tB * tB;
            #pragma unroll
            for (int off = 16; off > 0; off >>= 1) {
                sumA += __shfl_xor(sumA, off); sqA += __shfl_xor(sqA, off);
                sumB += __shfl_xor(sumB, off); sqB += __shfl_xor(sqB, off);
            }
            const float muA = sumA * (1.0f / 32.0f);
            const float rsA = rsqrtf(sqA * (1.0f / 32.0f) - muA * muA + 1e-5f);
            const float muB = sumB * (1.0f / 32.0f);
            const float rsB = rsqrtf(sqB * (1.0f / 32.0f) - muB * muB + 1e-5f);
            const float g2 = f_ln2_g[layer * 32 + j], be2 = f_ln2_b[layer * 32 + j];
            zlocA = (tA - muA) * rsA * g2 + be2;
            zlocB = (tB - muB) * rsB * g2 + be2;
            sZ[sA][j] = zlocA;
            sZ[sB][j] = zlocB;
        }
        __syncthreads();   // b5 (next layer QKV reads sZ)
    }
    // ---- final LN (in-wave, on register stream) + transposed zf write ----
    {
        float sumA = zlocA, sqA = zlocA * zlocA, sumB = zlocB, sqB = zlocB * zlocB;
        #pragma unroll
        for (int off = 16; off > 0; off >>= 1) {
            sumA += __shfl_xor(sumA, off); sqA += __shfl_xor(sqA, off);
            sumB += __shfl_xor(sumB, off); sqB += __shfl_xor(sqB, off);
        }
        const float muA = sumA * (1.0f / 32.0f);
        const float rsA = rsqrtf(sqA * (1.0f / 32.0f) - muA * muA + 1e-5f);
        const float muB = sumB * (1.0f / 32.0f);
        const float rsB = rsqrtf(sqB * (1.0f / 32.0f) - muB * muB + 1e-5f);
        const float gf = ln_f_g[j], bf = ln_f_b[j];
        sZf[j * 16 + sA] = (zlocA - muA) * rsA * gf + bf;   // zf[r*16+i], r=j, i=s
        sZf[j * 16 + sB] = (zlocB - muB) * rsB * gf + bf;
    }
    __syncthreads();
    // ---- head: out[o] = b_lin[o] + sum_j zf[j] * W_lin[j*96+o]; 2-way j-split ----
    if (tid < 192) {
        const int half = tid / 96, o = tid % 96;
        const int j0 = half * 256;
        float acc = 0.f;
        #pragma unroll 8
        for (int jj = 0; jj < 256; ++jj)
            acc = fmaf(sZf[j0 + jj], W_lin[(j0 + jj) * 96 + o], acc);
        sPart[half][o] = acc;
    }
    __syncthreads();
    if (tid < 96)
        out[((n >> 5) * 96 + tid) * 32 + (n & 31)] = sPart[0][tid] + sPart[1][tid] + b_lin[tid];
}

// ---------------------------------------------------------------------------
extern "C" void kernel_launch(void* const* d_in, const int* in_sizes, int n_in,
                              void* d_out, int out_size, void* d_ws, size_t ws_size,
                              hipStream_t stream) {
    const float* x       = (const float*)d_in[0];
    const float* x_mark  = (const float*)d_in[1];
    const float* x_mask  = (const float*)d_in[2];
    const float* Wq      = (const float*)d_in[3];
    const float* Wk      = (const float*)d_in[4];
    const float* W_out   = (const float*)d_in[5];
    const float* b_out   = (const float*)d_in[6];
    const float* f_Wq    = (const float*)d_in[7];
    const float* f_Wk    = (const float*)d_in[8];
    const float* f_Wv    = (const float*)d_in[9];
    const float* f_Wo    = (const float*)d_in[10];
    const float* f_bq    = (const float*)d_in[11];
    const float* f_bk    = (const float*)d_in[12];
    const float* f_bv    = (const float*)d_in[13];
    const float* f_bo    = (const float*)d_in[14];
    const float* f_ln1_g = (const float*)d_in[15];
    const float* f_ln1_b = (const float*)d_in[16];
    const float* f_W1    = (const float*)d_in[17];
    const float* f_b1    = (const float*)d_in[18];
    const float* f_W2    = (const float*)d_in[19];
    const float* f_b2    = (const float*)d_in[20];
    const float* f_ln2_g = (const float*)d_in[21];
    const float* f_ln2_b = (const float*)d_in[22];
    const float* ln_f_g  = (const float*)d_in[23];
    const float* ln_f_b  = (const float*)d_in[24];
    const float* W_lin   = (const float*)d_in[25];
    const float* b_lin   = (const float*)d_in[26];

    float* ws = (float*)d_ws;
    float* Kmat      = ws;                      // 4096*128 = 524288
    float* Qall      = ws + 524288;             // 512*128  = 65536
    unsigned* obsB   = (unsigned*)(ws + 589824);// 4096 words
    float* attn      = ws + 593920;             // 16*8*32*128 = 524288
    float* zbuf      = ws + 1118208;            // 256*16*32 = 131072   (total ~5.0 MB)

    k_embed_mm<<<1664, 256, 0, stream>>>(x_mark, Wk, Wq, x_mask, Kmat, Qall, obsB);
    k_patch_attn<<<512, 256, 0, stream>>>(x, x_mark, obsB, Kmat, Qall, attn);
    k_reprs<<<128, 256, 0, stream>>>(attn, W_out, b_out, zbuf);
    k_former<<<256, 256, 0, stream>>>(zbuf,
        f_Wq, f_Wk, f_Wv, f_Wo, f_bq, f_bk, f_bv, f_bo,
        f_ln1_g, f_ln1_b, f_W1, f_b1, f_W2, f_b2, f_ln2_g, f_ln2_b,
        ln_f_g, ln_f_b, W_lin, b_lin, (float*)d_out);
}